// Round 6
// baseline (522.266 us; speedup 1.0000x reference)
//
#include <hip/hip_runtime.h>

// ChainMessagePassing: out[n] = sum over edges with dst==n of x[src], two edge lists.
// x: [N=100000, 64] fp32; indices: [2, E=3200000] (src row 0, dst row 1), int64/int32.
//
// R6: fixed-capacity coarse buckets (no hist/scan), 64B-padded bucket cursors,
// and slab-MAJOR in-gather counting sort (key = (src_slab<<5)|dst_local) so all
// blocks sweep x slabs in lockstep -> sliding L2-sized window. Overflow edges
// (bucket fuller than cap) go to a list handled by a post-gather atomic cleanup.

static constexpr int D = 64;
static constexpr int Q = 16;           // float4 quads per row
static constexpr int NPB = 32;         // nodes per bucket
static constexpr int NPB_SHIFT = 5;
static constexpr int SLABS = 32;       // src slabs (x window = 1/32 of x per slab)
static constexpr int NBIN = NPB * SLABS;  // 1024 sort bins
static constexpr int CHUNK = 8192;     // edges per scatter block
static constexpr int CH = 2048;        // edges per gather sort chunk (8 KB LDS)
static constexpr int CURPAD = 16;      // ints per bucket cursor (one 64B line)

// ---- index dtype sniffer: int64 nonneg <2^31 has all-zero odd dwords ----
__global__ void detect_idx_dtype(const int* __restrict__ w, int* __restrict__ flag) {
    int tid = threadIdx.x;  // one wave
    int v = w[2 * tid + 1];
    unsigned long long m = __ballot(v != 0);
    if (tid == 0) *flag = (m == 0ULL) ? 1 : 0;
}

__device__ __forceinline__ int load_idx(const void* idx, long long i, int is64) {
    return is64 ? (int)((const long long*)idx)[i] : ((const int*)idx)[i];
}

// ---- phase 1: scatter packed (src<<5 | dst&31) into fixed-cap bucket bins ----
// Per-block two-pass: LDS count, reserve contiguous runs via one padded global
// atomic per (block,bucket), then write runs. Overflow -> list.
__global__ __launch_bounds__(256) void bucket_scatter_kernel(
        const void* __restrict__ up, const void* __restrict__ down,
        int* __restrict__ gcursor, unsigned* __restrict__ packed, int cap,
        int* __restrict__ ovf_cnt, int2* __restrict__ ovf_list, int ovf_cap,
        const int* __restrict__ flag, int E, int NB) {
    extern __shared__ int lds[];
    int* cnt = lds;        // [NB]
    int* base = lds + NB;  // [NB]
    const int is64 = *flag;
    const long long total = 2LL * E;
    const long long cs = (long long)blockIdx.x * CHUNK;
    if (cs >= total) return;
    const long long ce = min(total, cs + (long long)CHUNK);

    for (int i = threadIdx.x; i < NB; i += 256) cnt[i] = 0;
    __syncthreads();
    for (long long e = cs + threadIdx.x; e < ce; e += 256) {
        const void* idx = up; long long ee = e;
        if (ee >= E) { idx = down; ee -= E; }
        int dst = load_idx(idx, E + ee, is64);
        atomicAdd(&cnt[dst >> NPB_SHIFT], 1);
    }
    __syncthreads();
    for (int i = threadIdx.x; i < NB; i += 256) {
        int c = cnt[i];
        base[i] = c ? atomicAdd(&gcursor[i * CURPAD], c) : 0;
        cnt[i] = 0;  // reuse as local cursor
    }
    __syncthreads();
    for (long long e = cs + threadIdx.x; e < ce; e += 256) {
        const void* idx = up; long long ee = e;
        if (ee >= E) { idx = down; ee -= E; }
        int src = load_idx(idx, ee, is64);
        int dst = load_idx(idx, E + ee, is64);
        int b = dst >> NPB_SHIFT;
        int pos = base[b] + atomicAdd(&cnt[b], 1);
        if (pos < cap) {
            packed[(long long)b * cap + pos] =
                ((unsigned)src << NPB_SHIFT) | (unsigned)(dst & (NPB - 1));
        } else {
            int o = atomicAdd(ovf_cnt, 1);
            if (o < ovf_cap) ovf_list[o] = make_int2(src, dst);
        }
    }
}

// ---- phase 2: per-bucket counting sort by (slab MAJOR, dl minor) + register gather ----
// Whole block sweeps slabs 0..31 in order each chunk -> device-wide sliding
// x window ~1-3 slabs (< per-XCD L2). Group g (16 lanes) owns local nodes
// 2g, 2g+1; accumulates float4 quads in VGPRs. No atomics on output.
__global__ __launch_bounds__(256) void bucket_gather_kernel(
        const float* __restrict__ x, const int* __restrict__ gcursor,
        const unsigned* __restrict__ packed, int cap,
        float* __restrict__ out, int N, int sshift) {
    __shared__ unsigned sorted[CH];       // 8 KB
    __shared__ int cnt[NBIN];             // 4 KB
    __shared__ int binoff[NBIN + 1];      // 4 KB
    __shared__ int cursor[NBIN];          // 4 KB
    __shared__ int wsum[4];

    const int b = blockIdx.x;
    const int tid = threadIdx.x;
    const int g = tid >> 4;   // group 0..15
    const int q = tid & 15;   // quad within row
    const int lane = tid & 63;
    const int wv = tid >> 6;
    const long long pbase = (long long)b * cap;
    const int total = min(gcursor[b * CURPAD], cap);

    float4 acc[2];
    acc[0] = acc[1] = make_float4(0.f, 0.f, 0.f, 0.f);

    for (int cs0 = 0; cs0 < total; cs0 += CH) {
        const int m = min(CH, total - cs0);
        #pragma unroll
        for (int i = 0; i < NBIN / 256; i++) cnt[tid + 256 * i] = 0;
        __syncthreads();
        for (int i = tid; i < m; i += 256) {
            unsigned p = packed[pbase + cs0 + i];
            int key = ((int)((p >> NPB_SHIFT) >> sshift) << NPB_SHIFT) | (int)(p & (NPB - 1));
            atomicAdd(&cnt[key], 1);
        }
        __syncthreads();
        {   // block exclusive scan over NBIN bins (4 bins/thread)
            int b0 = cnt[4 * tid], b1 = cnt[4 * tid + 1];
            int b2 = cnt[4 * tid + 2], b3 = cnt[4 * tid + 3];
            int tsum = b0 + b1 + b2 + b3;
            int inc = tsum;
            #pragma unroll
            for (int off = 1; off < 64; off <<= 1) {
                int t = __shfl_up(inc, off, 64);
                if (lane >= off) inc += t;
            }
            if (lane == 63) wsum[wv] = inc;
            __syncthreads();
            int wbase = 0;
            #pragma unroll
            for (int w = 0; w < 4; w++) wbase += (w < wv) ? wsum[w] : 0;
            int excl = wbase + inc - tsum;
            binoff[4 * tid] = excl; cursor[4 * tid] = excl; excl += b0;
            binoff[4 * tid + 1] = excl; cursor[4 * tid + 1] = excl; excl += b1;
            binoff[4 * tid + 2] = excl; cursor[4 * tid + 2] = excl; excl += b2;
            binoff[4 * tid + 3] = excl; cursor[4 * tid + 3] = excl; excl += b3;
            if (tid == 255) binoff[NBIN] = excl;
        }
        __syncthreads();
        for (int i = tid; i < m; i += 256) {
            unsigned p = packed[pbase + cs0 + i];
            int key = ((int)((p >> NPB_SHIFT) >> sshift) << NPB_SHIFT) | (int)(p & (NPB - 1));
            int pos = atomicAdd(&cursor[key], 1);
            sorted[pos] = p;
        }
        __syncthreads();
        for (int s = 0; s < SLABS; s++) {   // slab-major sweep, block-synchronized
            #pragma unroll
            for (int j = 0; j < 2; j++) {
                const int bin = (s << NPB_SHIFT) | (2 * g + j);
                const int rb = binoff[bin], re = binoff[bin + 1];
                int e = rb;
                for (; e + 3 < re; e += 4) {  // 4 row-gathers in flight
                    unsigned p0 = sorted[e], p1 = sorted[e + 1];
                    unsigned p2 = sorted[e + 2], p3 = sorted[e + 3];
                    const float4 v0 = *(const float4*)(x + ((long long)(p0 >> NPB_SHIFT)) * D + q * 4);
                    const float4 v1 = *(const float4*)(x + ((long long)(p1 >> NPB_SHIFT)) * D + q * 4);
                    const float4 v2 = *(const float4*)(x + ((long long)(p2 >> NPB_SHIFT)) * D + q * 4);
                    const float4 v3 = *(const float4*)(x + ((long long)(p3 >> NPB_SHIFT)) * D + q * 4);
                    acc[j].x += (v0.x + v1.x) + (v2.x + v3.x);
                    acc[j].y += (v0.y + v1.y) + (v2.y + v3.y);
                    acc[j].z += (v0.z + v1.z) + (v2.z + v3.z);
                    acc[j].w += (v0.w + v1.w) + (v2.w + v3.w);
                }
                for (; e < re; e++) {
                    unsigned p = sorted[e];
                    const float4 v = *(const float4*)(x + ((long long)(p >> NPB_SHIFT)) * D + q * 4);
                    acc[j].x += v.x; acc[j].y += v.y; acc[j].z += v.z; acc[j].w += v.w;
                }
            }
        }
        __syncthreads();  // done reading sorted before next chunk reuses LDS
    }

    const int node0 = b * NPB;
    #pragma unroll
    for (int j = 0; j < 2; j++) {
        const int node = node0 + 2 * g + j;
        if (node < N)
            *(float4*)(out + (long long)node * D + q * 4) = acc[j];
    }
}

// ---- phase 3: cleanup of overflowed edges (runs after gather; usually ~25K edges) ----
__global__ __launch_bounds__(256) void cleanup_kernel(
        const float* __restrict__ x, const int* __restrict__ ovf_cnt,
        const int2* __restrict__ list, int ovf_cap, float* __restrict__ out) {
    const int cnt = min(*ovf_cnt, ovf_cap);
    const long long totalq = (long long)cnt * Q;
    const long long stride = (long long)gridDim.x * blockDim.x;
    for (long long t = (long long)blockIdx.x * blockDim.x + threadIdx.x;
         t < totalq; t += stride) {
        const int e = (int)(t >> 4);
        const int q = (int)(t & 15);
        const int2 sd = list[e];
        const float4 v = *(const float4*)(x + (long long)sd.x * D + q * 4);
        float* o = out + (long long)sd.y * D + q * 4;
        unsafeAtomicAdd(o + 0, v.x);
        unsafeAtomicAdd(o + 1, v.y);
        unsafeAtomicAdd(o + 2, v.z);
        unsafeAtomicAdd(o + 3, v.w);
    }
}

// ---- fallback: direct fp32 atomics (R1), needs no workspace ----
__global__ __launch_bounds__(256) void scatter_add_kernel(
        const float* __restrict__ x, const void* __restrict__ up_idx,
        const void* __restrict__ down_idx, float* __restrict__ out,
        const int* __restrict__ dtype_flag, int num_edges) {
    const int is64 = *dtype_flag;
    const long long total = 2LL * num_edges * Q;
    const long long stride = (long long)gridDim.x * blockDim.x;
    for (long long t = (long long)blockIdx.x * blockDim.x + threadIdx.x;
         t < total; t += stride) {
        const int quad = (int)(t & (Q - 1));
        long long eg = t >> 4;
        const void* idx = up_idx;
        if (eg >= num_edges) { idx = down_idx; eg -= num_edges; }
        int src = load_idx(idx, eg, is64);
        int dst = load_idx(idx, num_edges + eg, is64);
        const float4 v = *(const float4*)(x + (long long)src * D + quad * 4);
        float* o = out + (long long)dst * D + quad * 4;
        unsafeAtomicAdd(o + 0, v.x);
        unsafeAtomicAdd(o + 1, v.y);
        unsafeAtomicAdd(o + 2, v.z);
        unsafeAtomicAdd(o + 3, v.w);
    }
}

extern "C" void kernel_launch(void* const* d_in, const int* in_sizes, int n_in,
                              void* d_out, int out_size, void* d_ws, size_t ws_size,
                              hipStream_t stream) {
    const float* x = (const float*)d_in[0];
    const void* up_idx = d_in[1];
    const void* down_idx = d_in[2];
    float* out = (float*)d_out;

    const int E = in_sizes[1] / 2;   // [2, E]
    const int N = out_size / D;      // [N, 64]
    const int NB = (N + NPB - 1) / NPB;
    const long long Etot = 2LL * E;

    // slab shift: smallest s with (N-1)>>s < SLABS
    int sshift = 0;
    while (((unsigned)(N - 1) >> sshift) >= SLABS) sshift++;

    // ws layout (ints): flag(64) | gcursor[NB*CURPAD] | ovf_cnt(16) | ovf_list[2*ovf_cap] | packed[NB*cap]
    int* ws_i = (int*)d_ws;
    int* flag = ws_i;
    int* gcursor = ws_i + 64;
    int* ovf_cnt = gcursor + (long long)NB * CURPAD;
    const long long fixed = 64 + (long long)NB * CURPAD + 16;
    const long long avail = (long long)(ws_size / 4) - fixed;
    const long long capmin = (Etot + NB - 1) / NB;

    int ovf_cap = 1 << 20;
    long long cap = 0;
    for (;;) {
        cap = (avail - 2LL * ovf_cap) / NB;
        if (cap >= capmin || ovf_cap <= (1 << 14)) break;
        ovf_cap >>= 1;
    }
    if (cap > 8192) cap = 8192;
    int2* ovf_list = (int2*)(ovf_cnt + 16);
    unsigned* packed = (unsigned*)((int*)ovf_list + 2LL * ovf_cap);

    detect_idx_dtype<<<1, 64, 0, stream>>>((const int*)up_idx, flag);

    if (cap >= capmin && cap >= 1 && E >= 64 && N >= 1 &&
        N <= (1 << 23) && Etot < (1LL << 31)) {
        hipMemsetAsync(gcursor, 0, ((size_t)NB * CURPAD + 16) * sizeof(int), stream);
        const int sblocks = (int)((Etot + CHUNK - 1) / CHUNK);
        bucket_scatter_kernel<<<sblocks, 256, 2 * NB * sizeof(int), stream>>>(
            up_idx, down_idx, gcursor, packed, (int)cap,
            ovf_cnt, ovf_list, ovf_cap, flag, E, NB);
        bucket_gather_kernel<<<NB, 256, 0, stream>>>(
            x, gcursor, packed, (int)cap, out, N, sshift);
        cleanup_kernel<<<256, 256, 0, stream>>>(x, ovf_cnt, ovf_list, ovf_cap, out);
    } else {
        hipMemsetAsync(d_out, 0, (size_t)out_size * sizeof(float), stream);
        scatter_add_kernel<<<8192, 256, 0, stream>>>(x, up_idx, down_idx, out, flag, E);
    }
}

// Round 7
// 504.229 us; speedup vs baseline: 1.0358x; 1.0358x over previous
//
#include <hip/hip_runtime.h>

// ChainMessagePassing: out[n] = sum over edges with dst==n of x[src], two edge lists.
// x: [N=100000, 64] fp32; indices: [2, E=3200000] (src row 0, dst row 1), int64/int32.
//
// R7: exact-offset two-level radix partition + slab-major sorted gather.
//  hist(fine counts) -> scan -> passA (49 superbuckets, runs ~334 -> coalesced)
//  -> passB (32 fine buckets per SB, runs ~512 -> coalesced, exact offsets)
//  -> gather (per 64-node bucket; LDS counting sort by (src_slab<<6)|dst_local,
//     slab-major so all blocks sweep x slabs in lockstep -> sliding L2 window;
//     register accumulation, no atomics).
// R6's single-pass scatter wrote 277 MB for 25.6 MB payload (tiny runs ->
// cursor-frontier lines bouncing between non-coherent XCD L2s).

static constexpr int D = 64;
static constexpr int Q = 16;            // float4 quads per row
static constexpr int NPB = 64;          // nodes per fine bucket
static constexpr int NPB_SHIFT = 6;
static constexpr int FPSB = 32;         // fine buckets per superbucket
static constexpr int NPSB_SHIFT = 11;   // 2048 nodes per superbucket
static constexpr int SB_MASK = 2047;
static constexpr int SLABS = 16;        // src slabs in gather sort
static constexpr int NBIN = NPB * SLABS;  // 1024 gather sort bins
static constexpr int CHUNK = 16384;     // edges per partition block
static constexpr int CH = 4096;         // records per gather sort chunk
static constexpr int CURPAD = 16;       // ints per padded cursor (64B line)

// ---- index dtype sniffer: int64 nonneg <2^31 has all-zero odd dwords ----
__global__ void detect_idx_dtype(const int* __restrict__ w, int* __restrict__ flag) {
    int tid = threadIdx.x;  // one wave
    int v = w[2 * tid + 1];
    unsigned long long m = __ballot(v != 0);
    if (tid == 0) *flag = (m == 0ULL) ? 1 : 0;
}

__device__ __forceinline__ int load_idx(const void* idx, long long i, int is64) {
    return is64 ? (int)((const long long*)idx)[i] : ((const int*)idx)[i];
}

// ---- phase 1: fine-bucket histogram (LDS-aggregated) ----
__global__ __launch_bounds__(256) void hist_kernel(
        const void* __restrict__ up, const void* __restrict__ down,
        int* __restrict__ fineCnt, const int* __restrict__ flag, int E, int NB) {
    extern __shared__ int lcnt[];
    const int is64 = *flag;
    for (int i = threadIdx.x; i < NB; i += 256) lcnt[i] = 0;
    __syncthreads();
    const long long total = 2LL * E;
    const long long stride = (long long)gridDim.x * blockDim.x;
    for (long long e = (long long)blockIdx.x * blockDim.x + threadIdx.x;
         e < total; e += stride) {
        const void* idx = up; long long ee = e;
        if (ee >= E) { idx = down; ee -= E; }
        int dst = load_idx(idx, E + ee, is64);
        atomicAdd(&lcnt[dst >> NPB_SHIFT], 1);
    }
    __syncthreads();
    for (int i = threadIdx.x; i < NB; i += 256)
        if (lcnt[i]) atomicAdd(&fineCnt[i], lcnt[i]);
}

// ---- phase 2: exclusive scan -> fine offsets/cursors + SB boundaries/cursors ----
__global__ __launch_bounds__(1024) void scan_kernel(
        const int* __restrict__ fineCnt, int* __restrict__ fineOff,
        int* __restrict__ fineCur, int* __restrict__ sbOff,
        int* __restrict__ sbCur, int NB, int SB) {
    __shared__ int sums[1024];
    const int tid = threadIdx.x;
    const int chunk = (NB + 1023) / 1024;
    const int start = tid * chunk;
    const int end = min(start + chunk, NB);
    int s = 0;
    for (int i = start; i < end; i++) s += fineCnt[i];
    sums[tid] = s;
    __syncthreads();
    for (int off = 1; off < 1024; off <<= 1) {
        int t = (tid >= off) ? sums[tid - off] : 0;
        __syncthreads();
        sums[tid] += t;
        __syncthreads();
    }
    int run = (tid == 0) ? 0 : sums[tid - 1];
    for (int i = start; i < end; i++) {
        fineOff[i] = run;
        fineCur[i] = run;
        run += fineCnt[i];
    }
    if (tid == 1023) fineOff[NB] = run;
    __syncthreads();
    if (tid <= SB) {
        int v = fineOff[min(tid * FPSB, NB)];
        sbOff[tid] = v;
        if (tid < SB) sbCur[tid * CURPAD] = v;
    }
}

// ---- phase 3 (pass A): partition edges into SB regions; rec = (src<<11)|dst_local ----
__global__ __launch_bounds__(256) void passA_kernel(
        const void* __restrict__ up, const void* __restrict__ down,
        int* __restrict__ sbCur, unsigned* __restrict__ recA,
        const int* __restrict__ flag, int E, int SB) {
    __shared__ int cnt[64];
    __shared__ int base[64];
    const int is64 = *flag;
    const long long total = 2LL * E;
    const long long cs = (long long)blockIdx.x * CHUNK;
    if (cs >= total) return;
    const long long ce = min(total, cs + (long long)CHUNK);

    if (threadIdx.x < 64) cnt[threadIdx.x] = 0;
    __syncthreads();
    for (long long e = cs + threadIdx.x; e < ce; e += 256) {
        const void* idx = up; long long ee = e;
        if (ee >= E) { idx = down; ee -= E; }
        int dst = load_idx(idx, E + ee, is64);
        atomicAdd(&cnt[dst >> NPSB_SHIFT], 1);
    }
    __syncthreads();
    if (threadIdx.x < 64) {
        int i = threadIdx.x;
        int c = (i < SB) ? cnt[i] : 0;
        base[i] = c ? atomicAdd(&sbCur[i * CURPAD], c) : 0;
        cnt[i] = 0;  // local cursor
    }
    __syncthreads();
    for (long long e = cs + threadIdx.x; e < ce; e += 256) {
        const void* idx = up; long long ee = e;
        if (ee >= E) { idx = down; ee -= E; }
        int src = load_idx(idx, ee, is64);
        int dst = load_idx(idx, E + ee, is64);
        int k = dst >> NPSB_SHIFT;
        int pos = base[k] + atomicAdd(&cnt[k], 1);
        recA[pos] = ((unsigned)src << NPSB_SHIFT) | (unsigned)(dst & SB_MASK);
    }
}

// ---- phase 4 (pass B): within-SB partition to fine buckets at exact offsets ----
// SB id recovered positionally (binary search over sbOff); rec = (src<<6)|dl6.
__global__ __launch_bounds__(256) void passB_kernel(
        const unsigned* __restrict__ recA, const int* __restrict__ sbOffG,
        int* __restrict__ fineCur, unsigned* __restrict__ recB,
        long long total, int NB, int SB) {
    extern __shared__ int lds[];
    int* sbOff = lds;            // [SB+1]
    int* cnt = lds + SB + 1;     // [NB]
    int* base = cnt + NB;        // [NB]

    const long long cs = (long long)blockIdx.x * CHUNK;
    if (cs >= total) return;
    const long long ce = min(total, cs + (long long)CHUNK);

    for (int i = threadIdx.x; i <= SB; i += 256) sbOff[i] = sbOffG[i];
    for (int i = threadIdx.x; i < NB; i += 256) cnt[i] = 0;
    __syncthreads();

    for (long long i = cs + threadIdx.x; i < ce; i += 256) {
        // positional binary search: sb with sbOff[sb] <= i < sbOff[sb+1]
        int lo = 0, hi = SB - 1;
        while (lo < hi) {
            int mid = (lo + hi + 1) >> 1;
            if ((long long)sbOff[mid] <= i) lo = mid; else hi = mid - 1;
        }
        unsigned r = recA[i];
        int f = lo * FPSB + (int)((r & SB_MASK) >> NPB_SHIFT);
        atomicAdd(&cnt[f], 1);
    }
    __syncthreads();
    for (int i = threadIdx.x; i < NB; i += 256) {
        int c = cnt[i];
        base[i] = c ? atomicAdd(&fineCur[i], c) : 0;
        cnt[i] = 0;
    }
    __syncthreads();
    for (long long i = cs + threadIdx.x; i < ce; i += 256) {
        int lo = 0, hi = SB - 1;
        while (lo < hi) {
            int mid = (lo + hi + 1) >> 1;
            if ((long long)sbOff[mid] <= i) lo = mid; else hi = mid - 1;
        }
        unsigned r = recA[i];
        int dl = (int)(r & SB_MASK);
        int f = lo * FPSB + (dl >> NPB_SHIFT);
        int pos = base[f] + atomicAdd(&cnt[f], 1);
        recB[pos] = ((r >> NPSB_SHIFT) << NPB_SHIFT) | (unsigned)(dl & (NPB - 1));
    }
}

// ---- phase 5: per-bucket counting sort by (slab MAJOR, dl minor) + register gather ----
__global__ __launch_bounds__(256) void bucket_gather_kernel(
        const float* __restrict__ x, const int* __restrict__ fineOff,
        const unsigned* __restrict__ recB, float* __restrict__ out,
        int N, int sshift) {
    __shared__ unsigned sorted[CH];       // 16 KB
    __shared__ int cnt[NBIN];             // 4 KB
    __shared__ int binoff[NBIN + 1];      // 4 KB
    __shared__ int cursor[NBIN];          // 4 KB
    __shared__ int wsum[4];

    const int b = blockIdx.x;
    const int tid = threadIdx.x;
    const int g = tid >> 4;   // group 0..15
    const int q = tid & 15;   // quad within row
    const int lane = tid & 63;
    const int wv = tid >> 6;
    const int beg = fineOff[b], end = fineOff[b + 1];

    float4 acc[4];
    acc[0] = acc[1] = acc[2] = acc[3] = make_float4(0.f, 0.f, 0.f, 0.f);

    for (int cs = beg; cs < end; cs += CH) {
        const int m = min(CH, end - cs);
        #pragma unroll
        for (int i = 0; i < NBIN / 256; i++) cnt[tid + 256 * i] = 0;
        __syncthreads();
        for (int i = tid; i < m; i += 256) {
            unsigned p = recB[cs + i];
            int key = ((int)((p >> NPB_SHIFT) >> sshift) << NPB_SHIFT) | (int)(p & (NPB - 1));
            atomicAdd(&cnt[key], 1);
        }
        __syncthreads();
        {   // block exclusive scan over NBIN bins (4 bins/thread)
            int b0 = cnt[4 * tid], b1 = cnt[4 * tid + 1];
            int b2 = cnt[4 * tid + 2], b3 = cnt[4 * tid + 3];
            int tsum = b0 + b1 + b2 + b3;
            int inc = tsum;
            #pragma unroll
            for (int off = 1; off < 64; off <<= 1) {
                int t = __shfl_up(inc, off, 64);
                if (lane >= off) inc += t;
            }
            if (lane == 63) wsum[wv] = inc;
            __syncthreads();
            int wbase = 0;
            #pragma unroll
            for (int w = 0; w < 4; w++) wbase += (w < wv) ? wsum[w] : 0;
            int excl = wbase + inc - tsum;
            binoff[4 * tid] = excl; cursor[4 * tid] = excl; excl += b0;
            binoff[4 * tid + 1] = excl; cursor[4 * tid + 1] = excl; excl += b1;
            binoff[4 * tid + 2] = excl; cursor[4 * tid + 2] = excl; excl += b2;
            binoff[4 * tid + 3] = excl; cursor[4 * tid + 3] = excl; excl += b3;
            if (tid == 255) binoff[NBIN] = excl;
        }
        __syncthreads();
        for (int i = tid; i < m; i += 256) {
            unsigned p = recB[cs + i];
            int key = ((int)((p >> NPB_SHIFT) >> sshift) << NPB_SHIFT) | (int)(p & (NPB - 1));
            int pos = atomicAdd(&cursor[key], 1);
            sorted[pos] = p;
        }
        __syncthreads();
        for (int s = 0; s < SLABS; s++) {   // slab-major sweep, block-synchronized
            #pragma unroll
            for (int j = 0; j < 4; j++) {
                const int bin = (s << NPB_SHIFT) | (4 * g + j);
                const int rb = binoff[bin], re = binoff[bin + 1];
                int e = rb;
                for (; e + 3 < re; e += 4) {  // 4 row-gathers in flight
                    unsigned p0 = sorted[e], p1 = sorted[e + 1];
                    unsigned p2 = sorted[e + 2], p3 = sorted[e + 3];
                    const float4 v0 = *(const float4*)(x + ((long long)(p0 >> NPB_SHIFT)) * D + q * 4);
                    const float4 v1 = *(const float4*)(x + ((long long)(p1 >> NPB_SHIFT)) * D + q * 4);
                    const float4 v2 = *(const float4*)(x + ((long long)(p2 >> NPB_SHIFT)) * D + q * 4);
                    const float4 v3 = *(const float4*)(x + ((long long)(p3 >> NPB_SHIFT)) * D + q * 4);
                    acc[j].x += (v0.x + v1.x) + (v2.x + v3.x);
                    acc[j].y += (v0.y + v1.y) + (v2.y + v3.y);
                    acc[j].z += (v0.z + v1.z) + (v2.z + v3.z);
                    acc[j].w += (v0.w + v1.w) + (v2.w + v3.w);
                }
                for (; e < re; e++) {
                    unsigned p = sorted[e];
                    const float4 v = *(const float4*)(x + ((long long)(p >> NPB_SHIFT)) * D + q * 4);
                    acc[j].x += v.x; acc[j].y += v.y; acc[j].z += v.z; acc[j].w += v.w;
                }
            }
        }
        __syncthreads();  // done reading sorted before next chunk reuses LDS
    }

    const int node0 = b * NPB;
    #pragma unroll
    for (int j = 0; j < 4; j++) {
        const int node = node0 + 4 * g + j;
        if (node < N)
            *(float4*)(out + (long long)node * D + q * 4) = acc[j];
    }
}

// ---- fallback: direct fp32 atomics (R1), needs no workspace ----
__global__ __launch_bounds__(256) void scatter_add_kernel(
        const float* __restrict__ x, const void* __restrict__ up_idx,
        const void* __restrict__ down_idx, float* __restrict__ out,
        const int* __restrict__ dtype_flag, int num_edges) {
    const int is64 = *dtype_flag;
    const long long total = 2LL * num_edges * Q;
    const long long stride = (long long)gridDim.x * blockDim.x;
    for (long long t = (long long)blockIdx.x * blockDim.x + threadIdx.x;
         t < total; t += stride) {
        const int quad = (int)(t & (Q - 1));
        long long eg = t >> 4;
        const void* idx = up_idx;
        if (eg >= num_edges) { idx = down_idx; eg -= num_edges; }
        int src = load_idx(idx, eg, is64);
        int dst = load_idx(idx, num_edges + eg, is64);
        const float4 v = *(const float4*)(x + (long long)src * D + quad * 4);
        float* o = out + (long long)dst * D + quad * 4;
        unsafeAtomicAdd(o + 0, v.x);
        unsafeAtomicAdd(o + 1, v.y);
        unsafeAtomicAdd(o + 2, v.z);
        unsafeAtomicAdd(o + 3, v.w);
    }
}

extern "C" void kernel_launch(void* const* d_in, const int* in_sizes, int n_in,
                              void* d_out, int out_size, void* d_ws, size_t ws_size,
                              hipStream_t stream) {
    const float* x = (const float*)d_in[0];
    const void* up_idx = d_in[1];
    const void* down_idx = d_in[2];
    float* out = (float*)d_out;

    const int E = in_sizes[1] / 2;   // [2, E]
    const int N = out_size / D;      // [N, 64]
    const int NB = (N + NPB - 1) / NPB;
    const int SB = (NB + FPSB - 1) / FPSB;
    const long long Etot = 2LL * E;

    // slab shift: smallest s with (N-1)>>s < SLABS
    int sshift = 0;
    while (((unsigned)(N - 1) >> sshift) >= SLABS) sshift++;

    // ws layout (ints): flag(64) | fineCnt[NB] | fineOff[NB+1]+pad | fineCur[NB]
    //                   | sbOff[SB+1]+pad | sbCur[SB*CURPAD] | recA[Etot] | recB[Etot]
    int* ws_i = (int*)d_ws;
    int* flag = ws_i;
    int* fineCnt = ws_i + 64;
    int* fineOff = fineCnt + NB;
    int* fineCur = fineOff + NB + 1 + 15;
    int* sbOff = fineCur + NB;
    int* sbCur = sbOff + SB + 1 + 15;
    unsigned* recA = (unsigned*)(sbCur + (long long)SB * CURPAD);
    unsigned* recB = recA + Etot;
    const size_t ws_need = (size_t)(64 + 3LL * NB + 16 + SB + 16 +
                                    (long long)SB * CURPAD + 2LL * Etot) * 4 + 64;

    detect_idx_dtype<<<1, 64, 0, stream>>>((const int*)up_idx, flag);

    if (ws_size >= ws_need && E >= 64 && N >= 1 &&
        N <= (1 << 17) && SB <= 64 && Etot < (1LL << 31)) {
        hipMemsetAsync(fineCnt, 0, (size_t)NB * sizeof(int), stream);
        hist_kernel<<<1024, 256, NB * sizeof(int), stream>>>(
            up_idx, down_idx, fineCnt, flag, E, NB);
        scan_kernel<<<1, 1024, 0, stream>>>(fineCnt, fineOff, fineCur, sbOff, sbCur, NB, SB);
        const int pblocks = (int)((Etot + CHUNK - 1) / CHUNK);
        passA_kernel<<<pblocks, 256, 0, stream>>>(
            up_idx, down_idx, sbCur, recA, flag, E, SB);
        passB_kernel<<<pblocks, 256, (SB + 1 + 2 * NB) * sizeof(int), stream>>>(
            recA, sbOff, fineCur, recB, Etot, NB, SB);
        bucket_gather_kernel<<<NB, 256, 0, stream>>>(x, fineOff, recB, out, N, sshift);
    } else {
        hipMemsetAsync(d_out, 0, (size_t)out_size * sizeof(float), stream);
        scatter_add_kernel<<<8192, 256, 0, stream>>>(x, up_idx, down_idx, out, flag, E);
    }
}